// Round 1
// baseline (8217.481 us; speedup 1.0000x reference)
//
#include <hip/hip_runtime.h>

#define HH 96
#define WW 96
#define CCH 256
#define NPIX (HH*WW)       // 9216
#define DD (CCH*9)         // 2304
#define TN 128
#define TM 128
#define TK 16
#define KKN (DD/TK)        // 144
#define NT (NPIX/TN)       // 72
#define NPART 18
#define MT_PER (NT/NPART)  // 4

// ---------- kernel 1: style per-pixel sum of squares + reset keys ----------
__global__ __launch_bounds__(256) void prep_kernel(const float* __restrict__ Xs,
                                                   float* __restrict__ ssum,
                                                   unsigned long long* __restrict__ keys) {
    int p = blockIdx.x * 256 + threadIdx.x;
    if (p >= NPIX) return;
    float s = 0.f;
#pragma unroll 8
    for (int c = 0; c < CCH; ++c) {
        float v = Xs[c * NPIX + p];
        s = fmaf(v, v, s);
    }
    ssum[p] = s;
    keys[p] = 0ULL;   // must reset every launch (graph replay)
}

// ---------- kernel 2: 1 / max(patch_norm, 1e-12) for style ----------
__global__ __launch_bounds__(256) void rns_kernel(const float* __restrict__ ssum,
                                                  float* __restrict__ rns) {
    int p = blockIdx.x * 256 + threadIdx.x;
    if (p >= NPIX) return;
    int y = p / WW, x = p - y * WW;
    float s = 0.f;
    for (int dy = -1; dy <= 1; ++dy) {
        int yy = y + dy;
        if ((unsigned)yy >= HH) continue;
        for (int dx = -1; dx <= 1; ++dx) {
            int xx = x + dx;
            if ((unsigned)xx >= WW) continue;
            s += ssum[yy * WW + xx];
        }
    }
    rns[p] = 1.f / fmaxf(sqrtf(s), 1e-12f);
}

// ---------- kernel 3: fused unfold-GEMM + argmax ----------
// grid = NT * NPART blocks, 256 threads.
// Each block: one 128-row content tile x 4 style tiles (its m-part).
// Per-thread 8x8 register tile (rows {tr4+i, 64+tr4+i}, cols {tc4+j, 64+tc4+j}),
// TK=16 double-buffered LDS, unfold gathered on the fly.
__global__ __launch_bounds__(256, 2) void sim_argmax_kernel(
        const float* __restrict__ Xc, const float* __restrict__ Xs,
        const float* __restrict__ rns, unsigned long long* __restrict__ keys) {
    __shared__ __align__(16) float As[2][TK][TN];
    __shared__ __align__(16) float Bs[2][TK][TM];

    const int tid = threadIdx.x;
    const int nt = blockIdx.x % NT;
    const int part = blockIdx.x / NT;
    const int n0 = nt * TN;
    const int nn = tid & 127;
    const int hi = tid >> 7;          // 0/1: which k-parity group this thread stages
    const int n = n0 + nn;
    const int yn = n / WW, xn = n - yn * WW;
    const int tr4 = (tid >> 4) * 4;   // 0..60
    const int tc4 = (tid & 15) * 4;   // 0..60

    float best[8];
    int bidx[8];
#pragma unroll
    for (int i = 0; i < 8; ++i) { best[i] = -1e30f; bidx[i] = 0; }

    for (int mtl = 0; mtl < MT_PER; ++mtl) {
        const int mt = part * MT_PER + mtl;
        const int m_base = mt * TM;
        const int m = m_base + nn;
        const int ym = m / WW, xm = m - ym * WW;

        float acc[8][8];
#pragma unroll
        for (int i = 0; i < 8; ++i)
#pragma unroll
            for (int j = 0; j < 8; ++j) acc[i][j] = 0.f;

        // stage kk=0 into buffer 0
        {
#pragma unroll
            for (int q = 0; q < 8; ++q) {
                int k = hi + 2 * q;
                int d = k;                       // kk = 0
                int c = (d * 7282) >> 16;        // d/9 (valid for d < 9362)
                int r = d - 9 * c;
                int ki = (r * 11) >> 5;          // r/3
                int kj = r - 3 * ki;
                int ya = yn + ki - 1, xa = xn + kj - 1;
                As[0][k][nn] = ((unsigned)ya < HH && (unsigned)xa < WW)
                                   ? Xc[c * NPIX + ya * WW + xa] : 0.f;
                int yb = ym + ki - 1, xb = xm + kj - 1;
                Bs[0][k][nn] = ((unsigned)yb < HH && (unsigned)xb < WW)
                                   ? Xs[c * NPIX + yb * WW + xb] : 0.f;
            }
        }
        __syncthreads();

        for (int kk = 0; kk < KKN; ++kk) {
            const int cur = kk & 1;
            if (kk + 1 < KKN) {
                const int nxt = cur ^ 1;
                const int d0 = (kk + 1) * TK;
#pragma unroll
                for (int q = 0; q < 8; ++q) {
                    int k = hi + 2 * q;
                    int d = d0 + k;
                    int c = (d * 7282) >> 16;
                    int r = d - 9 * c;
                    int ki = (r * 11) >> 5;
                    int kj = r - 3 * ki;
                    int ya = yn + ki - 1, xa = xn + kj - 1;
                    As[nxt][k][nn] = ((unsigned)ya < HH && (unsigned)xa < WW)
                                         ? Xc[c * NPIX + ya * WW + xa] : 0.f;
                    int yb = ym + ki - 1, xb = xm + kj - 1;
                    Bs[nxt][k][nn] = ((unsigned)yb < HH && (unsigned)xb < WW)
                                         ? Xs[c * NPIX + yb * WW + xb] : 0.f;
                }
            }
#pragma unroll
            for (int k = 0; k < TK; ++k) {
                float av[8], bv[8];
                *(float4*)&av[0] = *(const float4*)&As[cur][k][tr4];
                *(float4*)&av[4] = *(const float4*)&As[cur][k][64 + tr4];
                *(float4*)&bv[0] = *(const float4*)&Bs[cur][k][tc4];
                *(float4*)&bv[4] = *(const float4*)&Bs[cur][k][64 + tc4];
#pragma unroll
                for (int i = 0; i < 8; ++i)
#pragma unroll
                    for (int j = 0; j < 8; ++j)
                        acc[i][j] = fmaf(av[i], bv[j], acc[i][j]);
            }
            __syncthreads();
        }

        // argmax update for this m-tile (m ascending within thread -> strict >)
#pragma unroll
        for (int j = 0; j < 8; ++j) {
            int mcol = (j < 4) ? (tc4 + j) : (64 + tc4 + j - 4);
            int mg = m_base + mcol;
            float sc = rns[mg];
#pragma unroll
            for (int i = 0; i < 8; ++i) {
                float v = acc[i][j] * sc;
                if (v > best[i]) { best[i] = v; bidx[i] = mg; }
            }
        }
    }

    // block reduce over the 16 column-threads of each row, then global atomicMax
    float* redV = (float*)&As[0][0][0];   // 128*16 floats = 8KB (aliases As[0])
    int* redI = (int*)&Bs[0][0][0];       // 8KB (aliases Bs[0])
    __syncthreads();
#pragma unroll
    for (int i = 0; i < 8; ++i) {
        int row = (i < 4) ? (tr4 + i) : (64 + tr4 + i - 4);
        redV[row * 16 + (tid & 15)] = best[i];
        redI[row * 16 + (tid & 15)] = bidx[i];
    }
    __syncthreads();
    if (tid < 128) {
        float bv = -1e30f; int bi = 0x7fffffff;
#pragma unroll
        for (int t = 0; t < 16; ++t) {
            float v = redV[tid * 16 + t];
            int id = redI[tid * 16 + t];
            if (v > bv || (v == bv && id < bi)) { bv = v; bi = id; }
        }
        // sortable float key; low word = ~idx so equal values prefer smaller m
        unsigned u = __float_as_uint(bv);
        unsigned key = (u & 0x80000000u) ? ~u : (u | 0x80000000u);
        unsigned long long k64 = ((unsigned long long)key << 32)
                               | (unsigned long long)(0xFFFFFFFFu - (unsigned)bi);
        atomicMax(&keys[n0 + tid], k64);
    }
}

// ---------- kernel 4: gather matched patches + fold + divide ----------
__global__ __launch_bounds__(256) void fold_kernel(const float* __restrict__ Xs,
                                                   const unsigned long long* __restrict__ keys,
                                                   float* __restrict__ out) {
    int e = blockIdx.x * 256 + threadIdx.x;   // e = c*NPIX + y*WW + x
    if (e >= CCH * NPIX) return;
    int c = e / NPIX;
    int p = e - c * NPIX;
    int y = p / WW, x = p - y * WW;
    float num = 0.f;
    int den = 0;
#pragma unroll
    for (int i = 0; i < 3; ++i) {
        int ny = y + 1 - i;
        if ((unsigned)ny >= HH) continue;
#pragma unroll
        for (int j = 0; j < 3; ++j) {
            int nx = x + 1 - j;
            if ((unsigned)nx >= WW) continue;
            den++;
            unsigned long long k64 = keys[ny * WW + nx];
            int mg = (int)(0xFFFFFFFFu - (unsigned)(k64 & 0xFFFFFFFFu));
            int my = mg / WW, mx = mg - my * WW;
            int sy = my + i - 1, sx = mx + j - 1;
            if ((unsigned)sy < HH && (unsigned)sx < WW)
                num += Xs[c * NPIX + sy * WW + sx];
        }
    }
    out[e] = num / ((float)den + 1e-8f);
}

extern "C" void kernel_launch(void* const* d_in, const int* in_sizes, int n_in,
                              void* d_out, int out_size, void* d_ws, size_t ws_size,
                              hipStream_t stream) {
    (void)in_sizes; (void)n_in; (void)out_size; (void)ws_size;
    const float* Xc = (const float*)d_in[0];   // content_features [256,96,96]
    const float* Xs = (const float*)d_in[1];   // style_features   [256,96,96]
    float* out = (float*)d_out;

    // ws layout: keys u64[9216] | ssum f32[9216] | rns f32[9216]  (~144 KB)
    unsigned long long* keys = (unsigned long long*)d_ws;
    float* ssum = (float*)((char*)d_ws + NPIX * 8);
    float* rns = (float*)((char*)d_ws + NPIX * 8 + NPIX * 4);

    prep_kernel<<<NPIX / 256, 256, 0, stream>>>(Xs, ssum, keys);
    rns_kernel<<<NPIX / 256, 256, 0, stream>>>(ssum, rns);
    sim_argmax_kernel<<<NT * NPART, 256, 0, stream>>>(Xc, Xs, rns, keys);
    fold_kernel<<<(CCH * NPIX) / 256, 256, 0, stream>>>(Xs, keys, out);
}

// Round 2
// 1203.758 us; speedup vs baseline: 6.8265x; 6.8265x over previous
//
#include <hip/hip_runtime.h>

#define HH 96
#define WW 96
#define CCH 256
#define NPIX (HH*WW)       // 9216
#define NT (NPIX/128)      // 72 n-tiles

// ---------- kernel 1: style per-pixel sum of squares + reset keys ----------
__global__ __launch_bounds__(256) void prep_kernel(const float* __restrict__ Xs,
                                                   float* __restrict__ ssum,
                                                   unsigned long long* __restrict__ keys) {
    int p = blockIdx.x * 256 + threadIdx.x;
    if (p >= NPIX) return;
    float s = 0.f;
#pragma unroll 8
    for (int c = 0; c < CCH; ++c) {
        float v = Xs[c * NPIX + p];
        s = fmaf(v, v, s);
    }
    ssum[p] = s;
    keys[p] = 0ULL;   // must reset every launch (graph replay)
}

// ---------- kernel 2: 1 / max(patch_norm, 1e-12) for style ----------
__global__ __launch_bounds__(256) void rns_kernel(const float* __restrict__ ssum,
                                                  float* __restrict__ rns) {
    int p = blockIdx.x * 256 + threadIdx.x;
    if (p >= NPIX) return;
    int y = p / WW, x = p - y * WW;
    float s = 0.f;
    for (int dy = -1; dy <= 1; ++dy) {
        int yy = y + dy;
        if ((unsigned)yy >= HH) continue;
        for (int dx = -1; dx <= 1; ++dx) {
            int xx = x + dx;
            if ((unsigned)xx >= WW) continue;
            s += ssum[yy * WW + xx];
        }
    }
    rns[p] = 1.f / fmaxf(sqrtf(s), 1e-12f);
}

// ---------- kernel 3: pixel-pixel channel-correlation GEMM ----------
// CC[p][q] = sum_c Xc[c,p] * Xs[c,q], for q in [cstart, cstart+Wpad) (cols
// beyond NPIX staged as 0). 128x128 tile, 8x8/thread, TK=16 double-buffered.
__global__ __launch_bounds__(256, 2) void cc_gemm_kernel(
        const float* __restrict__ Xc, const float* __restrict__ Xs,
        float* __restrict__ cc, int cstart, int Wpad) {
    __shared__ __align__(16) float As[2][16][128];
    __shared__ __align__(16) float Bs[2][16][128];

    const int tid = threadIdx.x;
    const int n0 = blockIdx.x * 128;
    const int mcol0 = blockIdx.y * 128;
    const int nn = tid & 127;
    const int klo = tid >> 7;
    const int tr4 = (tid >> 4) * 4;
    const int tc4 = (tid & 15) * 4;
    const int gB = cstart + mcol0 + nn;
    const bool okB = gB < NPIX;

#pragma unroll
    for (int q = 0; q < 8; ++q) {
        int k = klo + 2 * q;
        As[0][k][nn] = Xc[k * NPIX + n0 + nn];
        Bs[0][k][nn] = okB ? Xs[k * NPIX + gB] : 0.f;
    }
    __syncthreads();

    float acc[8][8];
#pragma unroll
    for (int i = 0; i < 8; ++i)
#pragma unroll
        for (int j = 0; j < 8; ++j) acc[i][j] = 0.f;

    for (int kk = 0; kk < 16; ++kk) {      // K = 256 = 16 * 16
        const int cur = kk & 1;
        if (kk < 15) {
            const int nxt = cur ^ 1;
            const int kb = (kk + 1) * 16;
#pragma unroll
            for (int q = 0; q < 8; ++q) {
                int k = klo + 2 * q;
                As[nxt][k][nn] = Xc[(kb + k) * NPIX + n0 + nn];
                Bs[nxt][k][nn] = okB ? Xs[(kb + k) * NPIX + gB] : 0.f;
            }
        }
#pragma unroll
        for (int k = 0; k < 16; ++k) {
            float av[8], bv[8];
            *(float4*)&av[0] = *(const float4*)&As[cur][k][tr4];
            *(float4*)&av[4] = *(const float4*)&As[cur][k][64 + tr4];
            *(float4*)&bv[0] = *(const float4*)&Bs[cur][k][tc4];
            *(float4*)&bv[4] = *(const float4*)&Bs[cur][k][64 + tc4];
#pragma unroll
            for (int i = 0; i < 8; ++i)
#pragma unroll
                for (int j = 0; j < 8; ++j)
                    acc[i][j] = fmaf(av[i], bv[j], acc[i][j]);
        }
        __syncthreads();
    }

#pragma unroll
    for (int i = 0; i < 8; ++i) {
        int row = (i < 4) ? (tr4 + i) : (64 + tr4 + i - 4);
        long long base = (long long)(n0 + row) * Wpad + mcol0;
        *(float4*)&cc[base + tc4]      = *(float4*)&acc[i][0];
        *(float4*)&cc[base + 64 + tc4] = *(float4*)&acc[i][4];
    }
}

// ---------- kernel 4: diagonal 3x3 box-sum over CC + argmax ----------
// sim(n,m) = sum_{di,dj} mask * CC[n + di*96+dj][m + di*96+dj], scaled by rns[m].
// Block: 16 n-rows (8 lane-groups x 2 iters), 32 m-lanes sweep the chunk.
__global__ __launch_bounds__(256) void boxsum_argmax_kernel(
        const float* __restrict__ cc, const float* __restrict__ rns,
        unsigned long long* __restrict__ keys,
        int m0, int Mc, int cstart, int Wpad) {
    const int tid = threadIdx.x;
    const int lane = tid & 31;
    const int grp = tid >> 5;

    for (int r = 0; r < 2; ++r) {
        const int n = blockIdx.x * 16 + grp + 8 * r;
        const int yn = ((n >> 5) * 21846) >> 16;   // n / 96
        const int xn = n - yn * WW;
        bool mn[9];
#pragma unroll
        for (int t = 0; t < 9; ++t) {
            int di = t / 3 - 1, dj = t % 3 - 1;
            mn[t] = ((unsigned)(yn + di) < HH) && ((unsigned)(xn + dj) < WW);
        }
        const long long baseN = (long long)n * Wpad - cstart;

        float best = -1e30f;
        int bidx = 0;
        for (int k = lane; k < Mc; k += 32) {
            const int m = m0 + k;
            const int ym = ((m >> 5) * 21846) >> 16;
            const int xm = m - ym * WW;
            float s = 0.f;
#pragma unroll
            for (int t = 0; t < 9; ++t) {
                int di = t / 3 - 1, dj = t % 3 - 1;
                int off = di * WW + dj;
                bool ok = mn[t] && ((unsigned)(ym + di) < HH) && ((unsigned)(xm + dj) < WW);
                float v = ok ? cc[baseN + m + (long long)off * (Wpad + 1)] : 0.f;
                s += v;
            }
            float v = s * rns[m];
            if (v > best) { best = v; bidx = m; }   // strict >: first (smallest m) wins
        }
#pragma unroll
        for (int d = 16; d; d >>= 1) {
            float ov = __shfl_xor(best, d);
            int oi = __shfl_xor(bidx, d);
            if (ov > best || (ov == best && oi < bidx)) { best = ov; bidx = oi; }
        }
        if (lane == 0) {
            unsigned u = __float_as_uint(best);
            unsigned key = (u & 0x80000000u) ? ~u : (u | 0x80000000u);
            unsigned long long k64 = ((unsigned long long)key << 32)
                                   | (unsigned long long)(0xFFFFFFFFu - (unsigned)bidx);
            atomicMax(&keys[n], k64);
        }
    }
}

// ---------- kernel 5: gather matched patches + fold + divide ----------
__global__ __launch_bounds__(256) void fold_kernel(const float* __restrict__ Xs,
                                                   const unsigned long long* __restrict__ keys,
                                                   float* __restrict__ out) {
    int e = blockIdx.x * 256 + threadIdx.x;   // e = c*NPIX + y*WW + x
    if (e >= CCH * NPIX) return;
    int c = e / NPIX;
    int p = e - c * NPIX;
    int y = p / WW, x = p - y * WW;
    float num = 0.f;
    int den = 0;
#pragma unroll
    for (int i = 0; i < 3; ++i) {
        int ny = y + 1 - i;
        if ((unsigned)ny >= HH) continue;
#pragma unroll
        for (int j = 0; j < 3; ++j) {
            int nx = x + 1 - j;
            if ((unsigned)nx >= WW) continue;
            den++;
            unsigned long long k64 = keys[ny * WW + nx];
            int mg = (int)(0xFFFFFFFFu - (unsigned)(k64 & 0xFFFFFFFFu));
            int my = mg / WW, mx = mg - my * WW;
            int sy = my + i - 1, sx = mx + j - 1;
            if ((unsigned)sy < HH && (unsigned)sx < WW)
                num += Xs[c * NPIX + sy * WW + sx];
        }
    }
    out[e] = num / ((float)den + 1e-8f);
}

extern "C" void kernel_launch(void* const* d_in, const int* in_sizes, int n_in,
                              void* d_out, int out_size, void* d_ws, size_t ws_size,
                              hipStream_t stream) {
    (void)in_sizes; (void)n_in; (void)out_size;
    const float* Xc = (const float*)d_in[0];   // content_features [256,96,96]
    const float* Xs = (const float*)d_in[1];   // style_features   [256,96,96]
    float* out = (float*)d_out;

    // ws layout: keys u64[9216] | ssum f32[9216] | rns f32[9216] | CC chunk
    unsigned long long* keys = (unsigned long long*)d_ws;
    float* ssum = (float*)((char*)d_ws + NPIX * 8);
    float* rns  = (float*)((char*)d_ws + NPIX * 8 + NPIX * 4);
    float* ccbuf = (float*)((char*)d_ws + NPIX * 16);
    const size_t fixed = (size_t)NPIX * 16;

    // Adaptive m-chunking: chunk Mc columns + 97-col halo each side fits ws.
    long long colcap = (ws_size > fixed)
                         ? (long long)((ws_size - fixed) / ((size_t)NPIX * 4)) : 0;
    int maxW = (int)((colcap / 128) * 128);
    if (maxW > NPIX) maxW = NPIX;
    int Mc;
    if (maxW >= NPIX) Mc = NPIX;
    else {
        Mc = ((maxW - 194) / 32) * 32;
        if (Mc < 32) Mc = 32;   // last resort (needs ~8.5 MB ws)
    }

    prep_kernel<<<NPIX / 256, 256, 0, stream>>>(Xs, ssum, keys);
    rns_kernel<<<NPIX / 256, 256, 0, stream>>>(ssum, rns);

    for (int m0 = 0; m0 < NPIX; m0 += Mc) {
        int mc = (Mc < NPIX - m0) ? Mc : (NPIX - m0);
        int cs = m0 - 97; if (cs < 0) cs = 0;
        int ce = m0 + mc + 97; if (ce > NPIX) ce = NPIX;
        int Wc = ce - cs;
        int Wpad = ((Wc + 127) / 128) * 128;
        dim3 g1(NT, Wpad / 128);
        cc_gemm_kernel<<<g1, 256, 0, stream>>>(Xc, Xs, ccbuf, cs, Wpad);
        boxsum_argmax_kernel<<<NPIX / 16, 256, 0, stream>>>(ccbuf, rns, keys,
                                                            m0, mc, cs, Wpad);
    }

    fold_kernel<<<(CCH * NPIX) / 256, 256, 0, stream>>>(Xs, keys, out);
}

// Round 3
// 842.487 us; speedup vs baseline: 9.7538x; 1.4288x over previous
//
#include <hip/hip_runtime.h>

#define HH 96
#define WW 96
#define CCH 256
#define NPIX (HH*WW)       // 9216
#define NT (NPIX/128)      // 72 n-tiles

typedef unsigned short u16;
typedef short bf16x8 __attribute__((ext_vector_type(8)));
typedef float f32x4 __attribute__((ext_vector_type(4)));

__device__ __forceinline__ u16 f2bf_rne(float x) {
    unsigned u = __float_as_uint(x);
    return (u16)((u + 0x7FFFu + ((u >> 16) & 1u)) >> 16);
}

// ---------- kernel 0: transpose + hi/lo bf16 split ----------
// X [256][9216] f32  ->  HiT/LoT [9216][256] bf16 bits (k contiguous)
__global__ __launch_bounds__(256) void tobf16_kernel(const float* __restrict__ X,
                                                     u16* __restrict__ HiT,
                                                     u16* __restrict__ LoT) {
    __shared__ u16 hi[64][65], lo[64][65];
    const int n0 = blockIdx.x * 64, k0 = blockIdx.y * 64;
    const int t = threadIdx.x;
    {
        const int kr = t >> 6, nl = t & 63;
#pragma unroll
        for (int r = 0; r < 16; ++r) {
            int kl = kr * 16 + r;
            float x = X[(k0 + kl) * NPIX + n0 + nl];
            u16 h = f2bf_rne(x);
            float hf = __uint_as_float((unsigned)h << 16);
            hi[kl][nl] = h;
            lo[kl][nl] = f2bf_rne(x - hf);
        }
    }
    __syncthreads();
    {
        const int nr = t >> 6, kl = t & 63;
#pragma unroll
        for (int r = 0; r < 16; ++r) {
            int nl = nr * 16 + r;
            HiT[(n0 + nl) * CCH + k0 + kl] = hi[kl][nl];
            LoT[(n0 + nl) * CCH + k0 + kl] = lo[kl][nl];
        }
    }
}

// ---------- kernel 1: style per-pixel sum of squares + reset keys ----------
__global__ __launch_bounds__(256) void prep_kernel(const float* __restrict__ Xs,
                                                   float* __restrict__ ssum,
                                                   unsigned long long* __restrict__ keys) {
    int p = blockIdx.x * 256 + threadIdx.x;
    if (p >= NPIX) return;
    float s = 0.f;
#pragma unroll 8
    for (int c = 0; c < CCH; ++c) {
        float v = Xs[c * NPIX + p];
        s = fmaf(v, v, s);
    }
    ssum[p] = s;
    keys[p] = 0ULL;   // reset every launch (graph replay)
}

// ---------- kernel 2: 1 / max(patch_norm, 1e-12) for style ----------
__global__ __launch_bounds__(256) void rns_kernel(const float* __restrict__ ssum,
                                                  float* __restrict__ rns) {
    int p = blockIdx.x * 256 + threadIdx.x;
    if (p >= NPIX) return;
    int y = p / WW, x = p - y * WW;
    float s = 0.f;
    for (int dy = -1; dy <= 1; ++dy) {
        int yy = y + dy;
        if ((unsigned)yy >= HH) continue;
        for (int dx = -1; dx <= 1; ++dx) {
            int xx = x + dx;
            if ((unsigned)xx >= WW) continue;
            s += ssum[yy * WW + xx];
        }
    }
    rns[p] = 1.f / fmaxf(sqrtf(s), 1e-12f);
}

// ---------- kernel 3: CC chunk GEMM via bf16 3-term-split MFMA ----------
// CC[p][q'] = sum_k Xc[k,p]*Xs[k,cstart+q'], computed as hh + hl + lh.
// Block 128(n) x 128(m), 4 waves in 2x2, each 64x64 via 4x4 16x16x32 frags.
__global__ __launch_bounds__(256, 2) void cc_gemm_kernel(
        const u16* __restrict__ ChiT, const u16* __restrict__ CloT,
        const u16* __restrict__ ShiT, const u16* __restrict__ SloT,
        float* __restrict__ cc, int cstart, int Wpad) {
    // [buf][arr: Ahi,Alo,Bhi,Blo][tile 0..7][lane 0..63][e 0..7]  = 64 KB
    __shared__ u16 lds[2][4][8][64][8];

    const int tid = threadIdx.x;
    const int n0 = blockIdx.x * 128;
    const int m0 = blockIdx.y * 128;
    const int st = tid >> 5;            // staging tile 0..7
    const int la = tid & 31;            // staging lane (also handles la+32)
    const int arow = n0 + st * 16 + (la & 15);
    const int bcol = cstart + m0 + st * 16 + (la & 15);
    const bool okb = bcol < NPIX;
    const int kwa = (la >> 4) * 8;      // k-window for lane la; +16 for la+32

    const u16* pA0 = ChiT + arow * CCH + kwa;
    const u16* pA1 = CloT + arow * CCH + kwa;
    const u16* pB0 = okb ? (ShiT + bcol * CCH + kwa) : nullptr;
    const u16* pB1 = okb ? (SloT + bcol * CCH + kwa) : nullptr;
    const bf16x8 zero = {0, 0, 0, 0, 0, 0, 0, 0};

#define STAGE(buf, kb)                                                          \
    do {                                                                        \
        *(bf16x8*)&lds[buf][0][st][la][0]      = *(const bf16x8*)(pA0 + (kb));  \
        *(bf16x8*)&lds[buf][0][st][la + 32][0] = *(const bf16x8*)(pA0 + (kb) + 16); \
        *(bf16x8*)&lds[buf][1][st][la][0]      = *(const bf16x8*)(pA1 + (kb));  \
        *(bf16x8*)&lds[buf][1][st][la + 32][0] = *(const bf16x8*)(pA1 + (kb) + 16); \
        if (okb) {                                                              \
            *(bf16x8*)&lds[buf][2][st][la][0]      = *(const bf16x8*)(pB0 + (kb));  \
            *(bf16x8*)&lds[buf][2][st][la + 32][0] = *(const bf16x8*)(pB0 + (kb) + 16); \
            *(bf16x8*)&lds[buf][3][st][la][0]      = *(const bf16x8*)(pB1 + (kb));  \
            *(bf16x8*)&lds[buf][3][st][la + 32][0] = *(const bf16x8*)(pB1 + (kb) + 16); \
        } else {                                                                \
            *(bf16x8*)&lds[buf][2][st][la][0] = zero;                           \
            *(bf16x8*)&lds[buf][2][st][la + 32][0] = zero;                      \
            *(bf16x8*)&lds[buf][3][st][la][0] = zero;                           \
            *(bf16x8*)&lds[buf][3][st][la + 32][0] = zero;                      \
        }                                                                       \
    } while (0)

    const int wave = tid >> 6, lane = tid & 63;
    const int wr = wave >> 1, wc = wave & 1;

    f32x4 acc[4][4];
#pragma unroll
    for (int i = 0; i < 4; ++i)
#pragma unroll
        for (int j = 0; j < 4; ++j) acc[i][j] = (f32x4){0.f, 0.f, 0.f, 0.f};

    STAGE(0, 0);
    __syncthreads();

    for (int kk = 0; kk < 8; ++kk) {        // K = 256 = 8 * 32
        const int cur = kk & 1;
        if (kk < 7) STAGE(cur ^ 1, (kk + 1) * 32);

        bf16x8 ah[4], al[4], bh[4], bl[4];
#pragma unroll
        for (int i = 0; i < 4; ++i) {
            ah[i] = *(const bf16x8*)&lds[cur][0][wr * 4 + i][lane][0];
            al[i] = *(const bf16x8*)&lds[cur][1][wr * 4 + i][lane][0];
            bh[i] = *(const bf16x8*)&lds[cur][2][wc * 4 + i][lane][0];
            bl[i] = *(const bf16x8*)&lds[cur][3][wc * 4 + i][lane][0];
        }
#pragma unroll
        for (int i = 0; i < 4; ++i)
#pragma unroll
            for (int j = 0; j < 4; ++j) {
                acc[i][j] = __builtin_amdgcn_mfma_f32_16x16x32_bf16(ah[i], bh[j], acc[i][j], 0, 0, 0);
                acc[i][j] = __builtin_amdgcn_mfma_f32_16x16x32_bf16(ah[i], bl[j], acc[i][j], 0, 0, 0);
                acc[i][j] = __builtin_amdgcn_mfma_f32_16x16x32_bf16(al[i], bh[j], acc[i][j], 0, 0, 0);
            }
        __syncthreads();
    }
#undef STAGE

    // C/D layout (HW-verified): col = lane&15, row = (lane>>4)*4 + reg
    const int r0 = (lane >> 4) * 4;
    const int cl = lane & 15;
#pragma unroll
    for (int i = 0; i < 4; ++i) {
        const int prow = n0 + wr * 64 + i * 16 + r0;
#pragma unroll
        for (int j = 0; j < 4; ++j) {
            const int q = m0 + wc * 64 + j * 16 + cl;
#pragma unroll
            for (int r = 0; r < 4; ++r)
                cc[(long long)(prow + r) * Wpad + q] = acc[i][j][r];
        }
    }
}

// ---------- kernel 4: diagonal 3x3 box-sum over CC + argmax ----------
__global__ __launch_bounds__(256) void boxsum_argmax_kernel(
        const float* __restrict__ cc, const float* __restrict__ rns,
        unsigned long long* __restrict__ keys,
        int m0, int Mc, int cstart, int Wpad) {
    const int tid = threadIdx.x;
    const int lane = tid & 31;
    const int grp = tid >> 5;

    for (int r = 0; r < 2; ++r) {
        const int n = blockIdx.x * 16 + grp + 8 * r;
        const int yn = ((n >> 5) * 21846) >> 16;   // n / 96
        const int xn = n - yn * WW;
        bool mn[9];
#pragma unroll
        for (int t = 0; t < 9; ++t) {
            int di = t / 3 - 1, dj = t % 3 - 1;
            mn[t] = ((unsigned)(yn + di) < HH) && ((unsigned)(xn + dj) < WW);
        }
        const long long baseN = (long long)n * Wpad - cstart;

        float best = -1e30f;
        int bidx = 0;
        for (int k = lane; k < Mc; k += 32) {
            const int m = m0 + k;
            const int ym = ((m >> 5) * 21846) >> 16;
            const int xm = m - ym * WW;
            float s = 0.f;
#pragma unroll
            for (int t = 0; t < 9; ++t) {
                int di = t / 3 - 1, dj = t % 3 - 1;
                int off = di * WW + dj;
                bool ok = mn[t] && ((unsigned)(ym + di) < HH) && ((unsigned)(xm + dj) < WW);
                float v = ok ? cc[baseN + m + (long long)off * (Wpad + 1)] : 0.f;
                s += v;
            }
            float v = s * rns[m];
            if (v > best) { best = v; bidx = m; }   // strict >: smallest m wins
        }
#pragma unroll
        for (int d = 16; d; d >>= 1) {
            float ov = __shfl_xor(best, d);
            int oi = __shfl_xor(bidx, d);
            if (ov > best || (ov == best && oi < bidx)) { best = ov; bidx = oi; }
        }
        if (lane == 0) {
            unsigned u = __float_as_uint(best);
            unsigned key = (u & 0x80000000u) ? ~u : (u | 0x80000000u);
            unsigned long long k64 = ((unsigned long long)key << 32)
                                   | (unsigned long long)(0xFFFFFFFFu - (unsigned)bidx);
            atomicMax(&keys[n], k64);
        }
    }
}

// ---------- kernel 5: gather matched patches + fold + divide ----------
__global__ __launch_bounds__(256) void fold_kernel(const float* __restrict__ Xs,
                                                   const unsigned long long* __restrict__ keys,
                                                   float* __restrict__ out) {
    int e = blockIdx.x * 256 + threadIdx.x;   // e = c*NPIX + y*WW + x
    if (e >= CCH * NPIX) return;
    int c = e / NPIX;
    int p = e - c * NPIX;
    int y = p / WW, x = p - y * WW;
    float num = 0.f;
    int den = 0;
#pragma unroll
    for (int i = 0; i < 3; ++i) {
        int ny = y + 1 - i;
        if ((unsigned)ny >= HH) continue;
#pragma unroll
        for (int j = 0; j < 3; ++j) {
            int nx = x + 1 - j;
            if ((unsigned)nx >= WW) continue;
            den++;
            unsigned long long k64 = keys[ny * WW + nx];
            int mg = (int)(0xFFFFFFFFu - (unsigned)(k64 & 0xFFFFFFFFu));
            int my = mg / WW, mx = mg - my * WW;
            int sy = my + i - 1, sx = mx + j - 1;
            if ((unsigned)sy < HH && (unsigned)sx < WW)
                num += Xs[c * NPIX + sy * WW + sx];
        }
    }
    out[e] = num / ((float)den + 1e-8f);
}

extern "C" void kernel_launch(void* const* d_in, const int* in_sizes, int n_in,
                              void* d_out, int out_size, void* d_ws, size_t ws_size,
                              hipStream_t stream) {
    (void)in_sizes; (void)n_in; (void)out_size;
    const float* Xc = (const float*)d_in[0];   // content_features [256,96,96]
    const float* Xs = (const float*)d_in[1];   // style_features   [256,96,96]
    float* out = (float*)d_out;

    // ws layout: keys u64[9216] | ssum | rns | ChiT | CloT | ShiT | SloT | CC chunk
    char* w = (char*)d_ws;
    unsigned long long* keys = (unsigned long long*)w;            w += (size_t)NPIX * 8;
    float* ssum = (float*)w;                                      w += (size_t)NPIX * 4;
    float* rns  = (float*)w;                                      w += (size_t)NPIX * 4;
    u16* ChiT = (u16*)w;                                          w += (size_t)NPIX * CCH * 2;
    u16* CloT = (u16*)w;                                          w += (size_t)NPIX * CCH * 2;
    u16* ShiT = (u16*)w;                                          w += (size_t)NPIX * CCH * 2;
    u16* SloT = (u16*)w;                                          w += (size_t)NPIX * CCH * 2;
    float* ccbuf = (float*)w;
    const size_t fixed = (size_t)(w - (char*)d_ws);

    long long colcap = (ws_size > fixed)
                         ? (long long)((ws_size - fixed) / ((size_t)NPIX * 4)) : 0;
    int Mc = 2304;                       // chunk ~94 MB -> L3-resident
    while (Mc > 144 && ((Mc + 194 + 127) / 128) * 128 > colcap) Mc >>= 1;

    dim3 gt(NPIX / 64, CCH / 64);
    tobf16_kernel<<<gt, 256, 0, stream>>>(Xc, ChiT, CloT);
    tobf16_kernel<<<gt, 256, 0, stream>>>(Xs, ShiT, SloT);
    prep_kernel<<<NPIX / 256, 256, 0, stream>>>(Xs, ssum, keys);
    rns_kernel<<<NPIX / 256, 256, 0, stream>>>(ssum, rns);

    for (int m0 = 0; m0 < NPIX; m0 += Mc) {
        int mc = (Mc < NPIX - m0) ? Mc : (NPIX - m0);
        int cs = m0 - 97; if (cs < 0) cs = 0;
        int ce = m0 + mc + 97; if (ce > NPIX) ce = NPIX;
        int Wpad = ((ce - cs + 127) / 128) * 128;
        dim3 g1(NT, Wpad / 128);
        cc_gemm_kernel<<<g1, 256, 0, stream>>>(ChiT, CloT, ShiT, SloT, ccbuf, cs, Wpad);
        boxsum_argmax_kernel<<<NPIX / 16, 256, 0, stream>>>(ccbuf, rns, keys,
                                                            m0, mc, cs, Wpad);
    }

    fold_kernel<<<(CCH * NPIX) / 256, 256, 0, stream>>>(Xs, keys, out);
}

// Round 4
// 503.559 us; speedup vs baseline: 16.3188x; 1.6731x over previous
//
#include <hip/hip_runtime.h>

#define HH 96
#define WW 96
#define CCH 256
#define NPIX (HH*WW)       // 9216
#define HP 98              // padded grid side
#define NROWS 9604         // 98*98 padded diag rows
#define CORE_LO 99         // first real padded index
#define CORE_HI 9505       // one past last real padded index (9504)

typedef unsigned short u16;
typedef short bf16x8 __attribute__((ext_vector_type(8)));
typedef float f32x4 __attribute__((ext_vector_type(4)));
typedef int i32x4 __attribute__((ext_vector_type(4)));

__device__ __forceinline__ f32x4 ld4u(const float* p) {
    f32x4 r; __builtin_memcpy(&r, p, 16); return r;
}
__device__ __forceinline__ i32x4 ld4ui(const int* p) {
    i32x4 r; __builtin_memcpy(&r, p, 16); return r;
}

__device__ __forceinline__ u16 f2bf_rne(float x) {
    unsigned u = __float_as_uint(x);
    return (u16)((u + 0x7FFFu + ((u >> 16) & 1u)) >> 16);
}

// ---------- kernel 0: transpose + hi/lo bf16 split ----------
__global__ __launch_bounds__(256) void tobf16_kernel(const float* __restrict__ X,
                                                     u16* __restrict__ HiT,
                                                     u16* __restrict__ LoT) {
    __shared__ u16 hi[64][65], lo[64][65];
    const int n0 = blockIdx.x * 64, k0 = blockIdx.y * 64;
    const int t = threadIdx.x;
    {
        const int kr = t >> 6, nl = t & 63;
#pragma unroll
        for (int r = 0; r < 16; ++r) {
            int kl = kr * 16 + r;
            float x = X[(k0 + kl) * NPIX + n0 + nl];
            u16 h = f2bf_rne(x);
            float hf = __uint_as_float((unsigned)h << 16);
            hi[kl][nl] = h;
            lo[kl][nl] = f2bf_rne(x - hf);
        }
    }
    __syncthreads();
    {
        const int nr = t >> 6, kl = t & 63;
#pragma unroll
        for (int r = 0; r < 16; ++r) {
            int nl = nr * 16 + r;
            HiT[(n0 + nl) * CCH + k0 + kl] = hi[kl][nl];
            LoT[(n0 + nl) * CCH + k0 + kl] = lo[kl][nl];
        }
    }
}

// ---------- kernel 1: style per-pixel channel sum-of-squares + reset keys ----------
__global__ __launch_bounds__(256) void prep_kernel(const float* __restrict__ Xs,
                                                   float* __restrict__ ssum,
                                                   unsigned long long* __restrict__ keys) {
    int p = blockIdx.x * 256 + threadIdx.x;
    if (p >= NPIX) return;
    float s = 0.f;
#pragma unroll 8
    for (int c = 0; c < CCH; ++c) {
        float v = Xs[c * NPIX + p];
        s = fmaf(v, v, s);
    }
    ssum[p] = s;
    keys[p] = 0ULL;   // reset every launch (graph replay)
}

// ---------- kernel 2: per padded-col tables: rns, bias(-inf on pad), midx ----------
__global__ __launch_bounds__(256) void rnsbp_kernel(const float* __restrict__ ssum,
                                                    float* __restrict__ rnsp,
                                                    float* __restrict__ biasp,
                                                    int* __restrict__ midxp) {
    int mp = blockIdx.x * 256 + threadIdx.x;
    if (mp >= 9632) return;
    int yq = mp / HP, xq = mp - yq * HP;
    bool real = (yq >= 1 && yq <= 96 && xq >= 1 && xq <= 96);
    if (!real) { rnsp[mp] = 0.f; biasp[mp] = -3e38f; midxp[mp] = 0; return; }
    int y = yq - 1, x = xq - 1;
    float s = 0.f;
    for (int dy = -1; dy <= 1; ++dy) {
        int yy = y + dy;
        if ((unsigned)yy >= HH) continue;
        for (int dx = -1; dx <= 1; ++dx) {
            int xx = x + dx;
            if ((unsigned)xx >= WW) continue;
            s += ssum[yy * WW + xx];
        }
    }
    rnsp[mp] = 1.f / fmaxf(sqrtf(s), 1e-12f);
    biasp[mp] = 0.f;
    midxp[mp] = y * WW + x;
}

// ---------- kernel 3: zero all pad rows of the padded CC buffer (once/launch) ----------
__global__ __launch_bounds__(256) void padzero_kernel(float* __restrict__ cc, int wstride) {
    int p = blockIdx.x;   // padded row
    int yq = p / HP, xq = p - yq * HP;
    if (yq >= 1 && yq <= 96 && xq >= 1 && xq <= 96) return;  // real row: GEMM writes it
    const f32x4 z = {0.f, 0.f, 0.f, 0.f};
    float* row = cc + (long long)p * wstride;
    for (int c = threadIdx.x * 4; c < wstride; c += 1024)
        *(f32x4*)&row[c] = z;
}

// ---------- kernel 4: CC chunk GEMM (bf16 3-term split MFMA), padded-col output ----------
__global__ __launch_bounds__(256, 2) void cc_gemm_kernel(
        const u16* __restrict__ ChiT, const u16* __restrict__ CloT,
        const u16* __restrict__ ShiT, const u16* __restrict__ SloT,
        float* __restrict__ cc, int csp, int wstride) {
    __shared__ u16 lds[2][4][8][64][8];   // [buf][Ahi,Alo,Bhi,Blo][tile][lane][e]

    const int tid = threadIdx.x;
    const int n0 = blockIdx.x * 128;
    const int m0 = blockIdx.y * 128;
    const int st = tid >> 5;
    const int la = tid & 31;
    const int arow = n0 + st * 16 + (la & 15);
    const int qp = csp + m0 + st * 16 + (la & 15);   // padded col index
    const int yq = qp / HP, xq = qp - yq * HP;
    const bool okb = (qp < NROWS) && (yq >= 1 && yq <= 96 && xq >= 1 && xq <= 96);
    const int bm = okb ? ((yq - 1) * WW + (xq - 1)) : 0;
    const int kwa = (la >> 4) * 8;

    const u16* pA0 = ChiT + arow * CCH + kwa;
    const u16* pA1 = CloT + arow * CCH + kwa;
    const u16* pB0 = ShiT + bm * CCH + kwa;
    const u16* pB1 = SloT + bm * CCH + kwa;
    const bf16x8 zero = {0, 0, 0, 0, 0, 0, 0, 0};

#define STAGE(buf, kb)                                                          \
    do {                                                                        \
        *(bf16x8*)&lds[buf][0][st][la][0]      = *(const bf16x8*)(pA0 + (kb));  \
        *(bf16x8*)&lds[buf][0][st][la + 32][0] = *(const bf16x8*)(pA0 + (kb) + 16); \
        *(bf16x8*)&lds[buf][1][st][la][0]      = *(const bf16x8*)(pA1 + (kb));  \
        *(bf16x8*)&lds[buf][1][st][la + 32][0] = *(const bf16x8*)(pA1 + (kb) + 16); \
        if (okb) {                                                              \
            *(bf16x8*)&lds[buf][2][st][la][0]      = *(const bf16x8*)(pB0 + (kb));  \
            *(bf16x8*)&lds[buf][2][st][la + 32][0] = *(const bf16x8*)(pB0 + (kb) + 16); \
            *(bf16x8*)&lds[buf][3][st][la][0]      = *(const bf16x8*)(pB1 + (kb));  \
            *(bf16x8*)&lds[buf][3][st][la + 32][0] = *(const bf16x8*)(pB1 + (kb) + 16); \
        } else {                                                                \
            *(bf16x8*)&lds[buf][2][st][la][0] = zero;                           \
            *(bf16x8*)&lds[buf][2][st][la + 32][0] = zero;                      \
            *(bf16x8*)&lds[buf][3][st][la][0] = zero;                           \
            *(bf16x8*)&lds[buf][3][st][la + 32][0] = zero;                      \
        }                                                                       \
    } while (0)

    const int wave = tid >> 6, lane = tid & 63;
    const int wr = wave >> 1, wc = wave & 1;

    f32x4 acc[4][4];
#pragma unroll
    for (int i = 0; i < 4; ++i)
#pragma unroll
        for (int j = 0; j < 4; ++j) acc[i][j] = (f32x4){0.f, 0.f, 0.f, 0.f};

    STAGE(0, 0);
    __syncthreads();

    for (int kk = 0; kk < 8; ++kk) {        // K = 256 = 8 * 32
        const int cur = kk & 1;
        if (kk < 7) STAGE(cur ^ 1, (kk + 1) * 32);

        bf16x8 ah[4], al[4], bh[4], bl[4];
#pragma unroll
        for (int i = 0; i < 4; ++i) {
            ah[i] = *(const bf16x8*)&lds[cur][0][wr * 4 + i][lane][0];
            al[i] = *(const bf16x8*)&lds[cur][1][wr * 4 + i][lane][0];
            bh[i] = *(const bf16x8*)&lds[cur][2][wc * 4 + i][lane][0];
            bl[i] = *(const bf16x8*)&lds[cur][3][wc * 4 + i][lane][0];
        }
#pragma unroll
        for (int i = 0; i < 4; ++i)
#pragma unroll
            for (int j = 0; j < 4; ++j) {
                acc[i][j] = __builtin_amdgcn_mfma_f32_16x16x32_bf16(ah[i], bh[j], acc[i][j], 0, 0, 0);
                acc[i][j] = __builtin_amdgcn_mfma_f32_16x16x32_bf16(ah[i], bl[j], acc[i][j], 0, 0, 0);
                acc[i][j] = __builtin_amdgcn_mfma_f32_16x16x32_bf16(al[i], bh[j], acc[i][j], 0, 0, 0);
            }
        __syncthreads();
    }
#undef STAGE

    // C/D layout: col = lane&15, row = (lane>>4)*4 + reg. Rows remapped to padded p'.
    const int r0 = (lane >> 4) * 4;
    const int cl = lane & 15;
#pragma unroll
    for (int i = 0; i < 4; ++i) {
        const int prow = n0 + wr * 64 + i * 16 + r0;
#pragma unroll
        for (int r = 0; r < 4; ++r) {
            const int row = prow + r;
            const int pp = row + 2 * (row / WW) + CORE_LO;
            const long long base = (long long)pp * wstride + m0 + wc * 64 + cl;
#pragma unroll
            for (int j = 0; j < 4; ++j)
                cc[base + j * 16] = acc[i][j][r];
        }
    }
}

// ---------- kernel 5: streaming 9-tap diagonal box-sum + argmax ----------
__global__ __launch_bounds__(256) void boxsum_kernel(
        const float* __restrict__ cc, const float* __restrict__ rnsp,
        const float* __restrict__ biasp, const int* __restrict__ midxp,
        unsigned long long* __restrict__ keys,
        int core0, int coreEnd, int csp, int wstride) {
    const int wave = threadIdx.x >> 6, lane = threadIdx.x & 63;
    const int n = blockIdx.x * 4 + wave;
    const int pp = n + 2 * (n / WW) + CORE_LO;
    const long long rowbase = (long long)pp * wstride - csp;
    const int W1 = wstride + 1;

    const int OFF[9] = {-99, -98, -97, -1, 0, 1, 97, 98, 99};
    const float* tp[9];
#pragma unroll
    for (int t = 0; t < 9; ++t)
        tp[t] = cc + rowbase + core0 + lane * 4 + (long long)OFF[t] * W1;

    float best = -1e30f;
    int bidx = 0;
    for (int mq = core0 + lane * 4; mq < coreEnd; mq += 256) {
        f32x4 s = {0.f, 0.f, 0.f, 0.f};
#pragma unroll
        for (int t = 0; t < 9; ++t) { s += ld4u(tp[t]); tp[t] += 256; }
        f32x4 rv = ld4u(rnsp + mq);
        f32x4 bv = ld4u(biasp + mq);
        i32x4 iv = ld4ui(midxp + mq);
#pragma unroll
        for (int sl = 0; sl < 4; ++sl) {
            float v = fmaf(s[sl], rv[sl], bv[sl]);
            if (mq + sl >= coreEnd) v = -3e38f;
            if (v > best) { best = v; bidx = iv[sl]; }   // strict >: smallest m wins
        }
    }
#pragma unroll
    for (int d = 32; d; d >>= 1) {
        float ov = __shfl_xor(best, d);
        int oi = __shfl_xor(bidx, d);
        if (ov > best || (ov == best && oi < bidx)) { best = ov; bidx = oi; }
    }
    if (lane == 0) {
        unsigned u = __float_as_uint(best);
        unsigned key = (u & 0x80000000u) ? ~u : (u | 0x80000000u);
        unsigned long long k64 = ((unsigned long long)key << 32)
                               | (unsigned long long)(0xFFFFFFFFu - (unsigned)bidx);
        atomicMax(&keys[n], k64);
    }
}

// ---------- kernel 6: gather matched patches + fold + divide ----------
__global__ __launch_bounds__(256) void fold_kernel(const float* __restrict__ Xs,
                                                   const unsigned long long* __restrict__ keys,
                                                   float* __restrict__ out) {
    int e = blockIdx.x * 256 + threadIdx.x;   // e = c*NPIX + y*WW + x
    if (e >= CCH * NPIX) return;
    int c = e / NPIX;
    int p = e - c * NPIX;
    int y = p / WW, x = p - y * WW;
    float num = 0.f;
    int den = 0;
#pragma unroll
    for (int i = 0; i < 3; ++i) {
        int ny = y + 1 - i;
        if ((unsigned)ny >= HH) continue;
#pragma unroll
        for (int j = 0; j < 3; ++j) {
            int nx = x + 1 - j;
            if ((unsigned)nx >= WW) continue;
            den++;
            unsigned long long k64 = keys[ny * WW + nx];
            int mg = (int)(0xFFFFFFFFu - (unsigned)(k64 & 0xFFFFFFFFu));
            int my = mg / WW, mx = mg - my * WW;
            int sy = my + i - 1, sx = mx + j - 1;
            if ((unsigned)sy < HH && (unsigned)sx < WW)
                num += Xs[c * NPIX + sy * WW + sx];
        }
    }
    out[e] = num / ((float)den + 1e-8f);
}

extern "C" void kernel_launch(void* const* d_in, const int* in_sizes, int n_in,
                              void* d_out, int out_size, void* d_ws, size_t ws_size,
                              hipStream_t stream) {
    (void)in_sizes; (void)n_in; (void)out_size;
    const float* Xc = (const float*)d_in[0];
    const float* Xs = (const float*)d_in[1];
    float* out = (float*)d_out;

    char* w = (char*)d_ws;
    unsigned long long* keys = (unsigned long long*)w;  w += (size_t)NPIX * 8;
    float* ssum  = (float*)w;                           w += (size_t)NPIX * 4;
    float* rnsp  = (float*)w;                           w += (size_t)9632 * 4;
    float* biasp = (float*)w;                           w += (size_t)9632 * 4;
    int*   midxp = (int*)w;                             w += (size_t)9632 * 4;
    u16* ChiT = (u16*)w;                                w += (size_t)NPIX * CCH * 2;
    u16* CloT = (u16*)w;                                w += (size_t)NPIX * CCH * 2;
    u16* ShiT = (u16*)w;                                w += (size_t)NPIX * CCH * 2;
    u16* SloT = (u16*)w;                                w += (size_t)NPIX * CCH * 2;
    float* ccbuf = (float*)w;
    const size_t fixed = (size_t)(w - (char*)d_ws);

    long long avail = (ws_size > fixed + 4096)
                        ? (long long)(ws_size - fixed - 4096) : 0;
    int wstride = (int)(((avail / ((long long)NROWS * 4)) / 128) * 128);
    if (wstride > 2560) wstride = 2560;
    if (wstride < 512) wstride = 512;
    const int McCore = wstride - 198;

    dim3 gt(NPIX / 64, CCH / 64);
    tobf16_kernel<<<gt, 256, 0, stream>>>(Xc, ChiT, CloT);
    tobf16_kernel<<<gt, 256, 0, stream>>>(Xs, ShiT, SloT);
    prep_kernel<<<NPIX / 256, 256, 0, stream>>>(Xs, ssum, keys);
    rnsbp_kernel<<<38, 256, 0, stream>>>(ssum, rnsp, biasp, midxp);
    padzero_kernel<<<NROWS, 256, 0, stream>>>(ccbuf, wstride);

    for (int core0 = CORE_LO; core0 < CORE_HI; core0 += McCore) {
        int coreEnd = (core0 + McCore < CORE_HI) ? core0 + McCore : CORE_HI;
        int csp = core0 - 99;
        int ce = coreEnd + 99; if (ce > NROWS) ce = NROWS;
        int Wc = ce - csp;
        dim3 g(NPIX / 128, (Wc + 127) / 128);
        cc_gemm_kernel<<<g, 256, 0, stream>>>(ChiT, CloT, ShiT, SloT, ccbuf, csp, wstride);
        boxsum_kernel<<<NPIX / 4, 256, 0, stream>>>(ccbuf, rnsp, biasp, midxp, keys,
                                                    core0, coreEnd, csp, wstride);
    }

    fold_kernel<<<(CCH * NPIX) / 256, 256, 0, stream>>>(Xs, keys, out);
}

// Round 5
// 452.458 us; speedup vs baseline: 18.1618x; 1.1129x over previous
//
#include <hip/hip_runtime.h>

#define HH 96
#define WW 96
#define CCH 256
#define NPIX (HH*WW)       // 9216
#define HP 98              // padded grid side
#define NROWS 9604         // 98*98 padded diag rows
#define CORE_LO 99         // first real padded index
#define CORE_HI 9505       // one past last real padded index

typedef unsigned short u16;
typedef short bf16x8 __attribute__((ext_vector_type(8)));
typedef float f32x4 __attribute__((ext_vector_type(4)));
typedef int i32x4 __attribute__((ext_vector_type(4)));

__device__ __forceinline__ f32x4 ld4u(const float* p) {
    f32x4 r; __builtin_memcpy(&r, p, 16); return r;
}
__device__ __forceinline__ i32x4 ld4ui(const int* p) {
    i32x4 r; __builtin_memcpy(&r, p, 16); return r;
}

__device__ __forceinline__ u16 f2bf_rne(float x) {
    unsigned u = __float_as_uint(x);
    return (u16)((u + 0x7FFFu + ((u >> 16) & 1u)) >> 16);
}

// async global->LDS, 16B per lane; dst is wave-uniform slab base
__device__ __forceinline__ void stage8(const u16* const* srcs, u16* dst, int kb) {
#pragma unroll
    for (int t = 0; t < 8; ++t)
        __builtin_amdgcn_global_load_lds(
            (const __attribute__((address_space(1))) unsigned int*)(srcs[t] + kb),
            (__attribute__((address_space(3))) unsigned int*)(dst + t * 512),
            16, 0, 0);
}

// ---------- kernel 0: transpose + hi/lo bf16 split ----------
__global__ __launch_bounds__(256) void tobf16_kernel(const float* __restrict__ X,
                                                     u16* __restrict__ HiT,
                                                     u16* __restrict__ LoT) {
    __shared__ u16 hi[64][65], lo[64][65];
    const int n0 = blockIdx.x * 64, k0 = blockIdx.y * 64;
    const int t = threadIdx.x;
    {
        const int kr = t >> 6, nl = t & 63;
#pragma unroll
        for (int r = 0; r < 16; ++r) {
            int kl = kr * 16 + r;
            float x = X[(k0 + kl) * NPIX + n0 + nl];
            u16 h = f2bf_rne(x);
            float hf = __uint_as_float((unsigned)h << 16);
            hi[kl][nl] = h;
            lo[kl][nl] = f2bf_rne(x - hf);
        }
    }
    __syncthreads();
    {
        const int nr = t >> 6, kl = t & 63;
#pragma unroll
        for (int r = 0; r < 16; ++r) {
            int nl = nr * 16 + r;
            HiT[(n0 + nl) * CCH + k0 + kl] = hi[kl][nl];
            LoT[(n0 + nl) * CCH + k0 + kl] = lo[kl][nl];
        }
    }
}

// ---------- kernel 0b: f32 transpose Xs [c][p] -> XsT [p][c] ----------
__global__ __launch_bounds__(256) void xst_kernel(const float* __restrict__ X,
                                                  float* __restrict__ XT) {
    __shared__ float tile[64][65];
    const int p0 = blockIdx.x * 64, c0 = blockIdx.y * 64;
    const int t = threadIdx.x;
    const int rr = t >> 6, cl = t & 63;
#pragma unroll
    for (int r = 0; r < 16; ++r)
        tile[rr * 16 + r][cl] = X[(c0 + rr * 16 + r) * NPIX + p0 + cl];
    __syncthreads();
#pragma unroll
    for (int r = 0; r < 16; ++r)
        XT[(p0 + rr * 16 + r) * CCH + c0 + cl] = tile[cl][rr * 16 + r];
}

// ---------- kernel 1: style per-pixel channel sum-of-squares + reset keys ----------
__global__ __launch_bounds__(256) void prep_kernel(const float* __restrict__ Xs,
                                                   float* __restrict__ ssum,
                                                   unsigned long long* __restrict__ keys) {
    int p = blockIdx.x * 256 + threadIdx.x;
    if (p >= NPIX) return;
    float s = 0.f;
#pragma unroll 8
    for (int c = 0; c < CCH; ++c) {
        float v = Xs[c * NPIX + p];
        s = fmaf(v, v, s);
    }
    ssum[p] = s;
    keys[p] = 0ULL;   // reset every launch (graph replay)
}

// ---------- kernel 2: per padded-col tables: rns, bias(-inf on pad), midx ----------
__global__ __launch_bounds__(256) void rnsbp_kernel(const float* __restrict__ ssum,
                                                    float* __restrict__ rnsp,
                                                    float* __restrict__ biasp,
                                                    int* __restrict__ midxp) {
    int mp = blockIdx.x * 256 + threadIdx.x;
    if (mp >= 9632) return;
    int yq = mp / HP, xq = mp - yq * HP;
    bool real = (yq >= 1 && yq <= 96 && xq >= 1 && xq <= 96);
    if (!real) { rnsp[mp] = 0.f; biasp[mp] = -3e38f; midxp[mp] = 0; return; }
    int y = yq - 1, x = xq - 1;
    float s = 0.f;
    for (int dy = -1; dy <= 1; ++dy) {
        int yy = y + dy;
        if ((unsigned)yy >= HH) continue;
        for (int dx = -1; dx <= 1; ++dx) {
            int xx = x + dx;
            if ((unsigned)xx >= WW) continue;
            s += ssum[yy * WW + xx];
        }
    }
    rnsp[mp] = 1.f / fmaxf(sqrtf(s), 1e-12f);
    biasp[mp] = 0.f;
    midxp[mp] = y * WW + x;
}

// ---------- kernel 3: zero all pad rows of the padded CC buffer ----------
__global__ __launch_bounds__(256) void padzero_kernel(float* __restrict__ cc, int wstride) {
    int p = blockIdx.x;   // padded row
    int yq = p / HP, xq = p - yq * HP;
    if (yq >= 1 && yq <= 96 && xq >= 1 && xq <= 96) return;  // real row: GEMM writes it
    const f32x4 z = {0.f, 0.f, 0.f, 0.f};
    float* row = cc + (long long)p * wstride;
    for (int c = threadIdx.x * 4; c < wstride; c += 1024)
        *(f32x4*)&row[c] = z;
}

// ---------- kernel 4: CC chunk GEMM (bf16 3-term split MFMA), gload_lds staging ----------
__global__ __launch_bounds__(256, 2) void cc_gemm_kernel(
        const u16* __restrict__ ChiT, const u16* __restrict__ CloT,
        const u16* __restrict__ ShiT, const u16* __restrict__ SloT,
        const u16* __restrict__ zbuf,
        float* __restrict__ cc, int csp, int wstride) {
    __shared__ u16 lds[2][4][8][64][8];   // [buf][Ahi,Alo,Bhi,Blo][tile][lane][e]

    const int tid = threadIdx.x;
    const int n0 = blockIdx.x * 128;
    const int m0 = blockIdx.y * 128;
    const int wave = tid >> 6, lane = tid & 63;
    const int wr = wave >> 1, wc = wave & 1;
    const int rlo = lane & 15, kseg = (lane >> 4) * 8;

    // wave w stages array w; per-tile per-lane source base (kb added later)
    const u16* srcs[8];
    if (wave < 2) {
        const u16* base = (wave == 0) ? ChiT : CloT;
#pragma unroll
        for (int t = 0; t < 8; ++t)
            srcs[t] = base + (n0 + t * 16 + rlo) * CCH + kseg;
    } else {
        const u16* base = (wave == 2) ? ShiT : SloT;
#pragma unroll
        for (int t = 0; t < 8; ++t) {
            int qp = csp + m0 + t * 16 + rlo;
            int yq = qp / HP, xq = qp - yq * HP;
            bool ok = (qp < NROWS) && (yq >= 1 && yq <= 96 && xq >= 1 && xq <= 96);
            srcs[t] = ok ? (base + ((yq - 1) * WW + (xq - 1)) * CCH + kseg)
                         : (zbuf + kseg);        // zbuf 1KB zeros; +kb stays inside
        }
    }
    u16* slab0 = &lds[0][wave][0][0][0];
    u16* slab1 = &lds[1][wave][0][0][0];

    f32x4 acc[4][4];
#pragma unroll
    for (int i = 0; i < 4; ++i)
#pragma unroll
        for (int j = 0; j < 4; ++j) acc[i][j] = (f32x4){0.f, 0.f, 0.f, 0.f};

    stage8(srcs, slab0, 0);
    __syncthreads();

    for (int kk = 0; kk < 8; ++kk) {        // K = 256 = 8 * 32
        const int cur = kk & 1;
        if (kk < 7) stage8(srcs, cur ? slab0 : slab1, (kk + 1) * 32);

        bf16x8 ah[4], al[4], bh[4], bl[4];
#pragma unroll
        for (int i = 0; i < 4; ++i) {
            ah[i] = *(const bf16x8*)&lds[cur][0][wr * 4 + i][lane][0];
            al[i] = *(const bf16x8*)&lds[cur][1][wr * 4 + i][lane][0];
            bh[i] = *(const bf16x8*)&lds[cur][2][wc * 4 + i][lane][0];
            bl[i] = *(const bf16x8*)&lds[cur][3][wc * 4 + i][lane][0];
        }
#pragma unroll
        for (int i = 0; i < 4; ++i)
#pragma unroll
            for (int j = 0; j < 4; ++j) {
                acc[i][j] = __builtin_amdgcn_mfma_f32_16x16x32_bf16(ah[i], bh[j], acc[i][j], 0, 0, 0);
                acc[i][j] = __builtin_amdgcn_mfma_f32_16x16x32_bf16(ah[i], bl[j], acc[i][j], 0, 0, 0);
                acc[i][j] = __builtin_amdgcn_mfma_f32_16x16x32_bf16(al[i], bh[j], acc[i][j], 0, 0, 0);
            }
        __syncthreads();
    }

    // C/D layout: col = lane&15, row = (lane>>4)*4 + reg. Rows remapped to padded p'.
    const int r0 = (lane >> 4) * 4;
    const int cl = lane & 15;
#pragma unroll
    for (int i = 0; i < 4; ++i) {
        const int prow = n0 + wr * 64 + i * 16 + r0;
#pragma unroll
        for (int r = 0; r < 4; ++r) {
            const int row = prow + r;
            const int pp = row + 2 * (row / WW) + CORE_LO;
            const long long base = (long long)pp * wstride + m0 + wc * 64 + cl;
#pragma unroll
            for (int j = 0; j < 4; ++j)
                cc[base + j * 16] = acc[i][j][r];
        }
    }
}

// ---------- kernel 5: streaming 9-tap diagonal box-sum + argmax ----------
__global__ __launch_bounds__(256) void boxsum_kernel(
        const float* __restrict__ cc, const float* __restrict__ rnsp,
        const float* __restrict__ biasp, const int* __restrict__ midxp,
        unsigned long long* __restrict__ keys,
        int core0, int coreEnd, int csp, int wstride) {
    const int wave = threadIdx.x >> 6, lane = threadIdx.x & 63;
    const int n = blockIdx.x * 4 + wave;
    const int pp = n + 2 * (n / WW) + CORE_LO;
    const long long rowbase = (long long)pp * wstride - csp;
    const int W1 = wstride + 1;

    const int OFF[9] = {-99, -98, -97, -1, 0, 1, 97, 98, 99};
    const float* tp[9];
#pragma unroll
    for (int t = 0; t < 9; ++t)
        tp[t] = cc + rowbase + core0 + lane * 4 + (long long)OFF[t] * W1;

    float best = -1e30f;
    int bidx = 0;
    for (int mq = core0 + lane * 4; mq < coreEnd; mq += 256) {
        f32x4 s = {0.f, 0.f, 0.f, 0.f};
#pragma unroll
        for (int t = 0; t < 9; ++t) { s += ld4u(tp[t]); tp[t] += 256; }
        f32x4 rv = ld4u(rnsp + mq);
        f32x4 bv = ld4u(biasp + mq);
        i32x4 iv = ld4ui(midxp + mq);
#pragma unroll
        for (int sl = 0; sl < 4; ++sl) {
            float v = fmaf(s[sl], rv[sl], bv[sl]);
            if (mq + sl >= coreEnd) v = -3e38f;
            if (v > best) { best = v; bidx = iv[sl]; }   // strict >: smallest m wins
        }
    }
#pragma unroll
    for (int d = 32; d; d >>= 1) {
        float ov = __shfl_xor(best, d);
        int oi = __shfl_xor(bidx, d);
        if (ov > best || (ov == best && oi < bidx)) { best = ov; bidx = oi; }
    }
    if (lane == 0) {
        unsigned u = __float_as_uint(best);
        unsigned key = (u & 0x80000000u) ? ~u : (u | 0x80000000u);
        unsigned long long k64 = ((unsigned long long)key << 32)
                               | (unsigned long long)(0xFFFFFFFFu - (unsigned)bidx);
        atomicMax(&keys[n], k64);
    }
}

// ---------- kernel 6: coalesced fold (one wave = one output pixel) ----------
__global__ __launch_bounds__(256) void fold2_kernel(const float* __restrict__ XsT,
                                                    const unsigned long long* __restrict__ keys,
                                                    float* __restrict__ outT) {
    const int wave = threadIdx.x >> 6, lane = threadIdx.x & 63;
    const int p = blockIdx.x * 4 + wave;
    const int y = p / WW, x = p - y * WW;
    f32x4 num = {0.f, 0.f, 0.f, 0.f};
    int den = 0;
#pragma unroll
    for (int i = 0; i < 3; ++i) {
        int ny = y + 1 - i;
        if ((unsigned)ny >= HH) continue;
#pragma unroll
        for (int j = 0; j < 3; ++j) {
            int nx = x + 1 - j;
            if ((unsigned)nx >= WW) continue;
            den++;
            unsigned long long k64 = keys[ny * WW + nx];
            int mg = (int)(0xFFFFFFFFu - (unsigned)(k64 & 0xFFFFFFFFu));
            int my = mg / WW, mx = mg - my * WW;
            int sy = my + i - 1, sx = mx + j - 1;
            if ((unsigned)sy < HH && (unsigned)sx < WW)
                num += ld4u(XsT + (long long)(sy * WW + sx) * CCH + lane * 4);
        }
    }
    float inv = 1.f / ((float)den + 1e-8f);
    f32x4 o = {num[0] * inv, num[1] * inv, num[2] * inv, num[3] * inv};
    *(f32x4*)&outT[(long long)p * CCH + lane * 4] = o;
}

// ---------- kernel 7: transpose outT [p][c] -> out [c][p] ----------
__global__ __launch_bounds__(256) void outtr_kernel(const float* __restrict__ outT,
                                                    float* __restrict__ out) {
    __shared__ float tile[64][65];
    const int p0 = blockIdx.x * 64, c0 = blockIdx.y * 64;
    const int t = threadIdx.x;
    const int rr = t >> 6, cl = t & 63;
#pragma unroll
    for (int r = 0; r < 16; ++r)
        tile[rr * 16 + r][cl] = outT[(long long)(p0 + rr * 16 + r) * CCH + c0 + cl];
    __syncthreads();
#pragma unroll
    for (int r = 0; r < 16; ++r)
        out[(long long)(c0 + rr * 16 + r) * NPIX + p0 + cl] = tile[cl][rr * 16 + r];
}

extern "C" void kernel_launch(void* const* d_in, const int* in_sizes, int n_in,
                              void* d_out, int out_size, void* d_ws, size_t ws_size,
                              hipStream_t stream) {
    (void)in_sizes; (void)n_in; (void)out_size;
    const float* Xc = (const float*)d_in[0];
    const float* Xs = (const float*)d_in[1];
    float* out = (float*)d_out;

    char* w = (char*)d_ws;
    unsigned long long* keys = (unsigned long long*)w;  w += (size_t)NPIX * 8;
    float* ssum  = (float*)w;                           w += (size_t)NPIX * 4;
    float* rnsp  = (float*)w;                           w += (size_t)9632 * 4;
    float* biasp = (float*)w;                           w += (size_t)9632 * 4;
    int*   midxp = (int*)w;                             w += (size_t)9632 * 4;
    u16*   zbuf  = (u16*)w;                             w += 1024;
    float* XsT   = (float*)w;                           w += (size_t)NPIX * CCH * 4;
    float* outT  = (float*)w;                           w += (size_t)NPIX * CCH * 4;
    u16* ChiT = (u16*)w;                                w += (size_t)NPIX * CCH * 2;
    u16* CloT = (u16*)w;                                w += (size_t)NPIX * CCH * 2;
    u16* ShiT = (u16*)w;                                w += (size_t)NPIX * CCH * 2;
    u16* SloT = (u16*)w;                                w += (size_t)NPIX * CCH * 2;
    float* ccbuf = (float*)w;
    const size_t fixed = (size_t)(w - (char*)d_ws);

    long long avail = (ws_size > fixed + 4096)
                        ? (long long)(ws_size - fixed - 4096) : 0;
    int wstride = (int)(((avail / ((long long)NROWS * 4)) / 128) * 128);
    if (wstride > 2560) wstride = 2560;
    if (wstride < 512) wstride = 512;
    const int McCore = wstride - 198;

    hipMemsetAsync(zbuf, 0, 1024, stream);
    dim3 gt(NPIX / 64, CCH / 64);
    tobf16_kernel<<<gt, 256, 0, stream>>>(Xc, ChiT, CloT);
    tobf16_kernel<<<gt, 256, 0, stream>>>(Xs, ShiT, SloT);
    xst_kernel<<<gt, 256, 0, stream>>>(Xs, XsT);
    prep_kernel<<<NPIX / 256, 256, 0, stream>>>(Xs, ssum, keys);
    rnsbp_kernel<<<38, 256, 0, stream>>>(ssum, rnsp, biasp, midxp);
    padzero_kernel<<<NROWS, 256, 0, stream>>>(ccbuf, wstride);

    for (int core0 = CORE_LO; core0 < CORE_HI; core0 += McCore) {
        int coreEnd = (core0 + McCore < CORE_HI) ? core0 + McCore : CORE_HI;
        int csp = core0 - 99;
        int ce = coreEnd + 99; if (ce > NROWS) ce = NROWS;
        int Wc = ce - csp;
        dim3 g(NPIX / 128, (Wc + 127) / 128);
        cc_gemm_kernel<<<g, 256, 0, stream>>>(ChiT, CloT, ShiT, SloT, zbuf,
                                              ccbuf, csp, wstride);
        boxsum_kernel<<<NPIX / 4, 256, 0, stream>>>(ccbuf, rnsp, biasp, midxp, keys,
                                                    core0, coreEnd, csp, wstride);
    }

    fold2_kernel<<<NPIX / 4, 256, 0, stream>>>(XsT, keys, outT);
    outtr_kernel<<<gt, 256, 0, stream>>>(outT, out);
}

// Round 6
// 447.726 us; speedup vs baseline: 18.3538x; 1.0106x over previous
//
#include <hip/hip_runtime.h>

#define HH 96
#define WW 96
#define CCH 256
#define NPIX (HH*WW)       // 9216
#define HP 98              // padded grid side
#define NROWS 9604         // 98*98 padded diag rows
#define CORE_LO 99         // first real padded index
#define CORE_HI 9505       // one past last real padded index

typedef unsigned short u16;
typedef short bf16x8 __attribute__((ext_vector_type(8)));
typedef float f32x4 __attribute__((ext_vector_type(4)));
typedef int i32x4 __attribute__((ext_vector_type(4)));

__device__ __forceinline__ f32x4 ld4u(const float* p) {
    f32x4 r; __builtin_memcpy(&r, p, 16); return r;
}
__device__ __forceinline__ i32x4 ld4ui(const int* p) {
    i32x4 r; __builtin_memcpy(&r, p, 16); return r;
}

__device__ __forceinline__ u16 f2bf_rne(float x) {
    unsigned u = __float_as_uint(x);
    return (u16)((u + 0x7FFFu + ((u >> 16) & 1u)) >> 16);
}

// async global->LDS, 16B per lane; dst is wave-uniform slab base
__device__ __forceinline__ void stage8(const u16* const* srcs, u16* dst, int kb) {
#pragma unroll
    for (int t = 0; t < 8; ++t)
        __builtin_amdgcn_global_load_lds(
            (const __attribute__((address_space(1))) unsigned int*)(srcs[t] + kb),
            (__attribute__((address_space(3))) unsigned int*)(dst + t * 512),
            16, 0, 0);
}

// ---------- kernel 0: transpose + hi/lo bf16 split ----------
__global__ __launch_bounds__(256) void tobf16_kernel(const float* __restrict__ X,
                                                     u16* __restrict__ HiT,
                                                     u16* __restrict__ LoT) {
    __shared__ u16 hi[64][65], lo[64][65];
    const int n0 = blockIdx.x * 64, k0 = blockIdx.y * 64;
    const int t = threadIdx.x;
    {
        const int kr = t >> 6, nl = t & 63;
#pragma unroll
        for (int r = 0; r < 16; ++r) {
            int kl = kr * 16 + r;
            float x = X[(k0 + kl) * NPIX + n0 + nl];
            u16 h = f2bf_rne(x);
            float hf = __uint_as_float((unsigned)h << 16);
            hi[kl][nl] = h;
            lo[kl][nl] = f2bf_rne(x - hf);
        }
    }
    __syncthreads();
    {
        const int nr = t >> 6, kl = t & 63;
#pragma unroll
        for (int r = 0; r < 16; ++r) {
            int nl = nr * 16 + r;
            HiT[(n0 + nl) * CCH + k0 + kl] = hi[kl][nl];
            LoT[(n0 + nl) * CCH + k0 + kl] = lo[kl][nl];
        }
    }
}

// ---------- kernel 0b: f32 transpose Xs [c][p] -> XsT [p][c] ----------
__global__ __launch_bounds__(256) void xst_kernel(const float* __restrict__ X,
                                                  float* __restrict__ XT) {
    __shared__ float tile[64][65];
    const int p0 = blockIdx.x * 64, c0 = blockIdx.y * 64;
    const int t = threadIdx.x;
    const int rr = t >> 6, cl = t & 63;
#pragma unroll
    for (int r = 0; r < 16; ++r)
        tile[rr * 16 + r][cl] = X[(c0 + rr * 16 + r) * NPIX + p0 + cl];
    __syncthreads();
#pragma unroll
    for (int r = 0; r < 16; ++r)
        XT[(p0 + rr * 16 + r) * CCH + c0 + cl] = tile[cl][rr * 16 + r];
}

// ---------- kernel 1: style per-pixel channel sum-of-squares + reset keys ----------
__global__ __launch_bounds__(256) void prep_kernel(const float* __restrict__ Xs,
                                                   float* __restrict__ ssum,
                                                   unsigned long long* __restrict__ keys) {
    int p = blockIdx.x * 256 + threadIdx.x;
    if (p >= NPIX) return;
    float s = 0.f;
#pragma unroll 8
    for (int c = 0; c < CCH; ++c) {
        float v = Xs[c * NPIX + p];
        s = fmaf(v, v, s);
    }
    ssum[p] = s;
    keys[p] = 0ULL;   // reset every launch (graph replay)
}

// ---------- kernel 2: per padded-col tables: rns, bias(-inf on pad), midx ----------
__global__ __launch_bounds__(256) void rnsbp_kernel(const float* __restrict__ ssum,
                                                    float* __restrict__ rnsp,
                                                    float* __restrict__ biasp,
                                                    int* __restrict__ midxp) {
    int mp = blockIdx.x * 256 + threadIdx.x;
    if (mp >= 9632) return;
    int yq = mp / HP, xq = mp - yq * HP;
    bool real = (yq >= 1 && yq <= 96 && xq >= 1 && xq <= 96);
    if (!real) { rnsp[mp] = 0.f; biasp[mp] = -3e38f; midxp[mp] = 0; return; }
    int y = yq - 1, x = xq - 1;
    float s = 0.f;
    for (int dy = -1; dy <= 1; ++dy) {
        int yy = y + dy;
        if ((unsigned)yy >= HH) continue;
        for (int dx = -1; dx <= 1; ++dx) {
            int xx = x + dx;
            if ((unsigned)xx >= WW) continue;
            s += ssum[yy * WW + xx];
        }
    }
    rnsp[mp] = 1.f / fmaxf(sqrtf(s), 1e-12f);
    biasp[mp] = 0.f;
    midxp[mp] = y * WW + x;
}

// ---------- kernel 3: zero all pad rows of the padded CC buffer ----------
__global__ __launch_bounds__(256) void padzero_kernel(float* __restrict__ cc, int wstride) {
    int p = blockIdx.x;   // padded row
    int yq = p / HP, xq = p - yq * HP;
    if (yq >= 1 && yq <= 96 && xq >= 1 && xq <= 96) return;  // real row: GEMM writes it
    const f32x4 z = {0.f, 0.f, 0.f, 0.f};
    float* row = cc + (long long)p * wstride;
    for (int c = threadIdx.x * 4; c < wstride; c += 1024)
        *(f32x4*)&row[c] = z;
}

// ---------- kernel 4: CC chunk GEMM, counted-vmcnt pipelined staging ----------
__global__ __launch_bounds__(256, 2) void cc_gemm_kernel(
        const u16* __restrict__ ChiT, const u16* __restrict__ CloT,
        const u16* __restrict__ ShiT, const u16* __restrict__ SloT,
        const u16* __restrict__ zbuf,
        float* __restrict__ cc, int csp, int wstride) {
    __shared__ u16 lds[2][4][8][64][8];   // [buf][Ahi,Alo,Bhi,Blo][tile][lane][e]

    const int tid = threadIdx.x;
    const int n0 = blockIdx.x * 128;
    const int m0 = blockIdx.y * 128;
    const int wave = tid >> 6, lane = tid & 63;
    const int wr = wave >> 1, wc = wave & 1;
    const int rlo = lane & 15, kseg = (lane >> 4) * 8;

    // wave w stages array w; per-tile per-lane source base (kb added later)
    const u16* srcs[8];
    if (wave < 2) {
        const u16* base = (wave == 0) ? ChiT : CloT;
#pragma unroll
        for (int t = 0; t < 8; ++t)
            srcs[t] = base + (n0 + t * 16 + rlo) * CCH + kseg;
    } else {
        const u16* base = (wave == 2) ? ShiT : SloT;
#pragma unroll
        for (int t = 0; t < 8; ++t) {
            int qp = csp + m0 + t * 16 + rlo;
            int yq = qp / HP, xq = qp - yq * HP;
            bool ok = (qp < NROWS) && (yq >= 1 && yq <= 96 && xq >= 1 && xq <= 96);
            srcs[t] = ok ? (base + ((yq - 1) * WW + (xq - 1)) * CCH + kseg)
                         : (zbuf + kseg);        // zbuf 1KB zeros; +kb stays inside
        }
    }
    u16* slab0 = &lds[0][wave][0][0][0];
    u16* slab1 = &lds[1][wave][0][0][0];

    f32x4 acc[4][4];
#pragma unroll
    for (int i = 0; i < 4; ++i)
#pragma unroll
        for (int j = 0; j < 4; ++j) acc[i][j] = (f32x4){0.f, 0.f, 0.f, 0.f};

    // prologue: groups 0,1 in flight (16 outstanding vmem ops)
    stage8(srcs, slab0, 0);
    stage8(srcs, slab1, 32);

#define READS(CUR)                                                          \
    bf16x8 ah[4], al[4], bh[4], bl[4];                                      \
    _Pragma("unroll")                                                       \
    for (int i = 0; i < 4; ++i) {                                           \
        ah[i] = *(const bf16x8*)&lds[CUR][0][wr * 4 + i][lane][0];          \
        al[i] = *(const bf16x8*)&lds[CUR][1][wr * 4 + i][lane][0];          \
        bh[i] = *(const bf16x8*)&lds[CUR][2][wc * 4 + i][lane][0];          \
        bl[i] = *(const bf16x8*)&lds[CUR][3][wc * 4 + i][lane][0];          \
    }

#define MFMAS                                                               \
    _Pragma("unroll")                                                       \
    for (int i = 0; i < 4; ++i)                                             \
        _Pragma("unroll")                                                   \
        for (int j = 0; j < 4; ++j) {                                       \
            acc[i][j] = __builtin_amdgcn_mfma_f32_16x16x32_bf16(ah[i], bh[j], acc[i][j], 0, 0, 0); \
            acc[i][j] = __builtin_amdgcn_mfma_f32_16x16x32_bf16(ah[i], bl[j], acc[i][j], 0, 0, 0); \
            acc[i][j] = __builtin_amdgcn_mfma_f32_16x16x32_bf16(al[i], bh[j], acc[i][j], 0, 0, 0); \
        }

    // Per step kk: wait ONLY the cur group's 8 loads (next group stays in
    // flight), barrier, ds_read cur, lgkmcnt(0), barrier (read-before-
    // overwrite), stage group kk+2 into freed buffer, MFMA on registers.
    // Outstanding-after-cur ledger: kk<=6 -> 8, kk==7 -> 0.
#define KSTEP(KK, WN)                                                       \
    {                                                                       \
        asm volatile("s_waitcnt vmcnt(" #WN ")" ::: "memory");              \
        __builtin_amdgcn_sched_barrier(0);                                  \
        __builtin_amdgcn_s_barrier();                                       \
        READS((KK) & 1)                                                     \
        asm volatile("s_waitcnt lgkmcnt(0)" ::: "memory");                  \
        __builtin_amdgcn_sched_barrier(0);                                  \
        __builtin_amdgcn_s_barrier();                                       \
        if ((KK) + 2 < 8)                                                   \
            stage8(srcs, (((KK) & 1)) ? slab1 : slab0, ((KK) + 2) * 32);    \
        __builtin_amdgcn_sched_barrier(0);                                  \
        MFMAS                                                               \
    }

    KSTEP(0, 8) KSTEP(1, 8) KSTEP(2, 8) KSTEP(3, 8)
    KSTEP(4, 8) KSTEP(5, 8) KSTEP(6, 8) KSTEP(7, 0)

#undef KSTEP
#undef MFMAS
#undef READS

    // C/D layout: col = lane&15, row = (lane>>4)*4 + reg. Rows remapped to padded p'.
    const int r0 = (lane >> 4) * 4;
    const int cl = lane & 15;
#pragma unroll
    for (int i = 0; i < 4; ++i) {
        const int prow = n0 + wr * 64 + i * 16 + r0;
#pragma unroll
        for (int r = 0; r < 4; ++r) {
            const int row = prow + r;
            const int pp = row + 2 * (row / WW) + CORE_LO;
            const long long base = (long long)pp * wstride + m0 + wc * 64 + cl;
#pragma unroll
            for (int j = 0; j < 4; ++j)
                cc[base + j * 16] = acc[i][j][r];
        }
    }
}

// ---------- kernel 5: streaming 9-tap diagonal box-sum + argmax ----------
__global__ __launch_bounds__(256) void boxsum_kernel(
        const float* __restrict__ cc, const float* __restrict__ rnsp,
        const float* __restrict__ biasp, const int* __restrict__ midxp,
        unsigned long long* __restrict__ keys,
        int core0, int coreEnd, int csp, int wstride) {
    const int wave = threadIdx.x >> 6, lane = threadIdx.x & 63;
    const int n = blockIdx.x * 4 + wave;
    const int pp = n + 2 * (n / WW) + CORE_LO;
    const long long rowbase = (long long)pp * wstride - csp;
    const int W1 = wstride + 1;

    const int OFF[9] = {-99, -98, -97, -1, 0, 1, 97, 98, 99};
    const float* tp[9];
#pragma unroll
    for (int t = 0; t < 9; ++t)
        tp[t] = cc + rowbase + core0 + lane * 4 + (long long)OFF[t] * W1;

    float best = -1e30f;
    int bidx = 0;
    for (int mq = core0 + lane * 4; mq < coreEnd; mq += 256) {
        f32x4 s = {0.f, 0.f, 0.f, 0.f};
#pragma unroll
        for (int t = 0; t < 9; ++t) { s += ld4u(tp[t]); tp[t] += 256; }
        f32x4 rv = ld4u(rnsp + mq);
        f32x4 bv = ld4u(biasp + mq);
        i32x4 iv = ld4ui(midxp + mq);
#pragma unroll
        for (int sl = 0; sl < 4; ++sl) {
            float v = fmaf(s[sl], rv[sl], bv[sl]);
            if (mq + sl >= coreEnd) v = -3e38f;
            if (v > best) { best = v; bidx = iv[sl]; }   // strict >: smallest m wins
        }
    }
#pragma unroll
    for (int d = 32; d; d >>= 1) {
        float ov = __shfl_xor(best, d);
        int oi = __shfl_xor(bidx, d);
        if (ov > best || (ov == best && oi < bidx)) { best = ov; bidx = oi; }
    }
    if (lane == 0) {
        unsigned u = __float_as_uint(best);
        unsigned key = (u & 0x80000000u) ? ~u : (u | 0x80000000u);
        unsigned long long k64 = ((unsigned long long)key << 32)
                               | (unsigned long long)(0xFFFFFFFFu - (unsigned)bidx);
        atomicMax(&keys[n], k64);
    }
}

// ---------- kernel 6: coalesced fold (one wave = one output pixel) ----------
__global__ __launch_bounds__(256) void fold2_kernel(const float* __restrict__ XsT,
                                                    const unsigned long long* __restrict__ keys,
                                                    float* __restrict__ outT) {
    const int wave = threadIdx.x >> 6, lane = threadIdx.x & 63;
    const int p = blockIdx.x * 4 + wave;
    const int y = p / WW, x = p - y * WW;
    f32x4 num = {0.f, 0.f, 0.f, 0.f};
    int den = 0;
#pragma unroll
    for (int i = 0; i < 3; ++i) {
        int ny = y + 1 - i;
        if ((unsigned)ny >= HH) continue;
#pragma unroll
        for (int j = 0; j < 3; ++j) {
            int nx = x + 1 - j;
            if ((unsigned)nx >= WW) continue;
            den++;
            unsigned long long k64 = keys[ny * WW + nx];
            int mg = (int)(0xFFFFFFFFu - (unsigned)(k64 & 0xFFFFFFFFu));
            int my = mg / WW, mx = mg - my * WW;
            int sy = my + i - 1, sx = mx + j - 1;
            if ((unsigned)sy < HH && (unsigned)sx < WW)
                num += ld4u(XsT + (long long)(sy * WW + sx) * CCH + lane * 4);
        }
    }
    float inv = 1.f / ((float)den + 1e-8f);
    f32x4 o = {num[0] * inv, num[1] * inv, num[2] * inv, num[3] * inv};
    *(f32x4*)&outT[(long long)p * CCH + lane * 4] = o;
}

// ---------- kernel 7: transpose outT [p][c] -> out [c][p] ----------
__global__ __launch_bounds__(256) void outtr_kernel(const float* __restrict__ outT,
                                                    float* __restrict__ out) {
    __shared__ float tile[64][65];
    const int p0 = blockIdx.x * 64, c0 = blockIdx.y * 64;
    const int t = threadIdx.x;
    const int rr = t >> 6, cl = t & 63;
#pragma unroll
    for (int r = 0; r < 16; ++r)
        tile[rr * 16 + r][cl] = outT[(long long)(p0 + rr * 16 + r) * CCH + c0 + cl];
    __syncthreads();
#pragma unroll
    for (int r = 0; r < 16; ++r)
        out[(long long)(c0 + rr * 16 + r) * NPIX + p0 + cl] = tile[cl][rr * 16 + r];
}

extern "C" void kernel_launch(void* const* d_in, const int* in_sizes, int n_in,
                              void* d_out, int out_size, void* d_ws, size_t ws_size,
                              hipStream_t stream) {
    (void)in_sizes; (void)n_in; (void)out_size;
    const float* Xc = (const float*)d_in[0];
    const float* Xs = (const float*)d_in[1];
    float* out = (float*)d_out;

    char* w = (char*)d_ws;
    unsigned long long* keys = (unsigned long long*)w;  w += (size_t)NPIX * 8;
    float* ssum  = (float*)w;                           w += (size_t)NPIX * 4;
    float* rnsp  = (float*)w;                           w += (size_t)9632 * 4;
    float* biasp = (float*)w;                           w += (size_t)9632 * 4;
    int*   midxp = (int*)w;                             w += (size_t)9632 * 4;
    u16*   zbuf  = (u16*)w;                             w += 1024;
    float* XsT   = (float*)w;                           w += (size_t)NPIX * CCH * 4;
    float* outT  = (float*)w;                           w += (size_t)NPIX * CCH * 4;
    u16* ChiT = (u16*)w;                                w += (size_t)NPIX * CCH * 2;
    u16* CloT = (u16*)w;                                w += (size_t)NPIX * CCH * 2;
    u16* ShiT = (u16*)w;                                w += (size_t)NPIX * CCH * 2;
    u16* SloT = (u16*)w;                                w += (size_t)NPIX * CCH * 2;
    float* ccbuf = (float*)w;
    const size_t fixed = (size_t)(w - (char*)d_ws);

    long long avail = (ws_size > fixed + 4096)
                        ? (long long)(ws_size - fixed - 4096) : 0;
    int wstride = (int)(((avail / ((long long)NROWS * 4)) / 128) * 128);
    if (wstride > 2560) wstride = 2560;
    if (wstride < 512) wstride = 512;
    const int McCore = wstride - 198;

    hipMemsetAsync(zbuf, 0, 1024, stream);
    dim3 gt(NPIX / 64, CCH / 64);
    tobf16_kernel<<<gt, 256, 0, stream>>>(Xc, ChiT, CloT);
    tobf16_kernel<<<gt, 256, 0, stream>>>(Xs, ShiT, SloT);
    xst_kernel<<<gt, 256, 0, stream>>>(Xs, XsT);
    prep_kernel<<<NPIX / 256, 256, 0, stream>>>(Xs, ssum, keys);
    rnsbp_kernel<<<38, 256, 0, stream>>>(ssum, rnsp, biasp, midxp);
    padzero_kernel<<<NROWS, 256, 0, stream>>>(ccbuf, wstride);

    for (int core0 = CORE_LO; core0 < CORE_HI; core0 += McCore) {
        int coreEnd = (core0 + McCore < CORE_HI) ? core0 + McCore : CORE_HI;
        int csp = core0 - 99;
        int ce = coreEnd + 99; if (ce > NROWS) ce = NROWS;
        int Wc = ce - csp;
        dim3 g(NPIX / 128, (Wc + 127) / 128);
        cc_gemm_kernel<<<g, 256, 0, stream>>>(ChiT, CloT, ShiT, SloT, zbuf,
                                              ccbuf, csp, wstride);
        boxsum_kernel<<<NPIX / 4, 256, 0, stream>>>(ccbuf, rnsp, biasp, midxp, keys,
                                                    core0, coreEnd, csp, wstride);
    }

    fold2_kernel<<<NPIX / 4, 256, 0, stream>>>(XsT, keys, outT);
    outtr_kernel<<<gt, 256, 0, stream>>>(outT, out);
}